// Round 15
// baseline (728.727 us; speedup 1.0000x reference)
//
#include <hip/hip_runtime.h>

#define THREADS 256
#define EB 256                 // number of edge blocks for bucketing (== THREADS)
#define BSHIFT 7
#define BROWS (1 << BSHIFT)    // 128 rows per bucket
#define MAXNB 1024             // static LDS bound: supports N up to 131072
#define COLBITS 17             // col < 131072
#define ACCW 66                // padded LDS stride (words) for 64-float acc rows

typedef float f32x4 __attribute__((ext_vector_type(4)));

// P1: per-edge-block histogram over row buckets (LDS atomics only).
__global__ void bucket_hist(const int* __restrict__ row, int* __restrict__ h,
                            int E, int per, int NB) {
    __shared__ int lds[MAXNB];
    for (int k = threadIdx.x; k < NB; k += blockDim.x) lds[k] = 0;
    __syncthreads();
    int lo = blockIdx.x * per;
    int hi = min(E, lo + per);
    for (int i = lo + threadIdx.x; i < hi; i += blockDim.x)
        atomicAdd(&lds[row[i] >> BSHIFT], 1);
    __syncthreads();
    int* hb = h + (size_t)blockIdx.x * NB;
    for (int k = threadIdx.x; k < NB; k += blockDim.x) hb[k] = lds[k];
}

// S1: exclusive scan down each bucket column of h. One block per bucket,
// 256 threads, one element per thread. Publishes per-bucket totals.
__global__ void scan_cols(int* __restrict__ h, int* __restrict__ totals, int NB) {
    __shared__ int wsum[THREADS / 64];
    __shared__ int wexcl[THREADS / 64];
    int k = blockIdx.x;
    size_t idx = (size_t)threadIdx.x * NB + k;
    int v = h[idx];
    int lane = threadIdx.x & 63, wid = threadIdx.x >> 6;
    int s = v;
#pragma unroll
    for (int off = 1; off < 64; off <<= 1) {
        int t = __shfl_up(s, off, 64);
        if (lane >= off) s += t;
    }
    if (lane == 63) wsum[wid] = s;
    __syncthreads();
    if (threadIdx.x == 0) {
        int run = 0;
#pragma unroll
        for (int w = 0; w < THREADS / 64; ++w) { wexcl[w] = run; run += wsum[w]; }
    }
    __syncthreads();
    int excl = wexcl[wid] + s - v;
    h[idx] = excl;
    if (threadIdx.x == THREADS - 1) totals[k] = excl + v;
}

// Redundant per-block exclusive scan of totals[0..NB-1] -> bs_l[0..NB].
__device__ __forceinline__ void scan_totals_lds(const int* __restrict__ totals,
                                                int* bs_l, int NB, int E) {
    __shared__ int wsum2[THREADS / 64];
    __shared__ int wexcl2[THREADS / 64];
    int base_i = threadIdx.x * 4;
    int v[4];
    int lsum = 0;
#pragma unroll
    for (int j = 0; j < 4; ++j) {
        v[j] = (base_i + j < NB) ? totals[base_i + j] : 0;
        lsum += v[j];
    }
    int lane = threadIdx.x & 63, wid = threadIdx.x >> 6;
    int ls = lsum;
#pragma unroll
    for (int off = 1; off < 64; off <<= 1) {
        int t = __shfl_up(ls, off, 64);
        if (lane >= off) ls += t;
    }
    if (lane == 63) wsum2[wid] = ls;
    __syncthreads();
    if (threadIdx.x == 0) {
        int run = 0;
#pragma unroll
        for (int w = 0; w < THREADS / 64; ++w) { wexcl2[w] = run; run += wsum2[w]; }
    }
    __syncthreads();
    int run = wexcl2[wid] + ls - lsum;
#pragma unroll
    for (int j = 0; j < 4; ++j) {
        if (base_i + j <= NB) bs_l[base_i + j] = run;
        run += v[j];
    }
    if (threadIdx.x == 0) bs_l[NB] = E;
    __syncthreads();
}

// P1b: scatter packed (lrow,col) u32 into bucket-sorted order.
__global__ void bucket_scatter(const int* __restrict__ row, const int* __restrict__ col,
                               const int* __restrict__ h, const int* __restrict__ totals,
                               unsigned* __restrict__ sorted,
                               int E, int per, int NB) {
    __shared__ int bs_l[MAXNB + 1];
    __shared__ int cur[MAXNB];
    scan_totals_lds(totals, bs_l, NB, E);
    const int* hb = h + (size_t)blockIdx.x * NB;
    for (int k = threadIdx.x; k < NB; k += blockDim.x) cur[k] = bs_l[k] + hb[k];
    __syncthreads();
    int lo = blockIdx.x * per;
    int hi = min(E, lo + per);
    for (int i = lo + threadIdx.x; i < hi; i += blockDim.x) {
        int r = row[i];
        int c = col[i];
        int pos = atomicAdd(&cur[r >> BSHIFT], 1);
        sorted[pos] = ((unsigned)(r & (BROWS - 1)) << COLBITS) | (unsigned)c;
    }
}

__device__ inline unsigned short bf16_rne(float f) {
    union { float f; unsigned u; } t; t.f = f;
    unsigned u = t.u;
    u += 0x7FFFu + ((u >> 16) & 1u);   // round to nearest even
    return (unsigned short)(u >> 16);
}

// P2a: one block per bucket: per-row degree (from sorted) -> dinv;
// then y = bf16(dinv*x) and out[:, :64] = x for this bucket's 128 nodes.
__global__ void bucket_dinv(const unsigned* __restrict__ sorted,
                            const int* __restrict__ totals,
                            const f32x4* __restrict__ x4,
                            float* __restrict__ dinv, f32x4* __restrict__ out4,
                            ushort4* __restrict__ y4, int N, int NB, int E) {
    __shared__ int bs_l[MAXNB + 1];
    __shared__ int hist[BROWS];
    __shared__ float dls[BROWS];
    scan_totals_lds(totals, bs_l, NB, E);
    int k = blockIdx.x;
    int base = bs_l[k];
    int cnt = bs_l[k + 1] - base;
    int base_node = k << BSHIFT;
    for (int r = threadIdx.x; r < BROWS; r += blockDim.x) hist[r] = 0;
    __syncthreads();
    for (int i = threadIdx.x; i < cnt; i += blockDim.x)
        atomicAdd(&hist[sorted[base + i] >> COLBITS], 1);
    __syncthreads();
    if (threadIdx.x < BROWS) {
        int v = hist[threadIdx.x];
        float w = (v > 0) ? rsqrtf((float)v) : 0.f;
        dls[threadIdx.x] = w;
        int node = base_node + threadIdx.x;
        if (node < N) dinv[node] = w;
    }
    __syncthreads();
    for (int t = threadIdx.x; t < BROWS * 16; t += blockDim.x) {
        int nl = t >> 4, q = t & 15;
        int node = base_node + nl;
        if (node >= N) break;
        f32x4 v = x4[(size_t)node * 16 + q];
        float w = dls[nl];
        out4[(size_t)node * 32 + q] = v;
        ushort4 hh;
        hh.x = bf16_rne(v.x * w);
        hh.y = bf16_rne(v.y * w);
        hh.z = bf16_rne(v.z * w);
        hh.w = bf16_rne(v.w * w);
        y4[(size_t)node * 16 + q] = hh;
    }
}

__device__ __forceinline__ void acc_edge_lds(float* acc, unsigned rc, uint4 v, int q) {
    float* a = acc + (size_t)(rc >> COLBITS) * ACCW + q * 8;
    atomicAdd(&a[0], __uint_as_float(v.x << 16));
    atomicAdd(&a[1], __uint_as_float(v.x & 0xFFFF0000u));
    atomicAdd(&a[2], __uint_as_float(v.y << 16));
    atomicAdd(&a[3], __uint_as_float(v.y & 0xFFFF0000u));
    atomicAdd(&a[4], __uint_as_float(v.z << 16));
    atomicAdd(&a[5], __uint_as_float(v.z & 0xFFFF0000u));
    atomicAdd(&a[6], __uint_as_float(v.w << 16));
    atomicAdd(&a[7], __uint_as_float(v.w & 0xFFFF0000u));
}

// P2b: one block per bucket: stream this bucket's edges from sorted,
// gather y[col] (128 B/edge across 8 lanes), accumulate into a 128x64 f32
// LDS tile via ds_add_f32, then write out[:, 64:] = dinv[node] * acc.
// Uniform per-edge work: no per-node loop, no CSR, no tail divergence
// (except the last partial 128-edge stripe).
__global__ void bucket_agg(const unsigned* __restrict__ sorted,
                           const int* __restrict__ totals,
                           const uint4* __restrict__ y16,
                           const float* __restrict__ dinv,
                           f32x4* __restrict__ out4, int N, int NB, int E) {
    __shared__ int bs_l[MAXNB + 1];
    __shared__ float acc[BROWS * ACCW];
    scan_totals_lds(totals, bs_l, NB, E);
    int k = blockIdx.x;
    int base = bs_l[k];
    int cnt = bs_l[k + 1] - base;
    int base_node = k << BSHIFT;
    for (int i = threadIdx.x; i < BROWS * ACCW; i += blockDim.x) acc[i] = 0.f;
    __syncthreads();

    const unsigned COLMASK = (1u << COLBITS) - 1;
    int gg = threadIdx.x >> 3;   // 0..31: edge slot within 32-edge stripe
    int q = threadIdx.x & 7;     // 0..7: 16B chunk of the 128B bf16 row
    for (int it = 0; it < cnt; it += 128) {
        int e0 = it + gg, e1 = it + 32 + gg, e2 = it + 64 + gg, e3 = it + 96 + gg;
        bool b0 = e0 < cnt, b1 = e1 < cnt, b2 = e2 < cnt, b3 = e3 < cnt;
        unsigned rc0 = 0, rc1 = 0, rc2 = 0, rc3 = 0;
        if (b0) rc0 = sorted[base + e0];
        if (b1) rc1 = sorted[base + e1];
        if (b2) rc2 = sorted[base + e2];
        if (b3) rc3 = sorted[base + e3];
        uint4 v0, v1, v2, v3;
        if (b0) v0 = y16[(size_t)(rc0 & COLMASK) * 8 + q];
        if (b1) v1 = y16[(size_t)(rc1 & COLMASK) * 8 + q];
        if (b2) v2 = y16[(size_t)(rc2 & COLMASK) * 8 + q];
        if (b3) v3 = y16[(size_t)(rc3 & COLMASK) * 8 + q];
        if (b0) acc_edge_lds(acc, rc0, v0, q);
        if (b1) acc_edge_lds(acc, rc1, v1, q);
        if (b2) acc_edge_lds(acc, rc2, v2, q);
        if (b3) acc_edge_lds(acc, rc3, v3, q);
    }
    __syncthreads();

    // out[node, 64:] = dinv[node] * acc[row]
    for (int t = threadIdx.x; t < BROWS * 16; t += blockDim.x) {
        int nl = t >> 4, qq = t & 15;
        int node = base_node + nl;
        if (node >= N) break;
        float w = dinv[node];
        const float* a = acc + (size_t)nl * ACCW + qq * 4;
        f32x4 r = {a[0] * w, a[1] * w, a[2] * w, a[3] * w};
        out4[(size_t)node * 32 + 16 + qq] = r;
    }
}

extern "C" void kernel_launch(void* const* d_in, const int* in_sizes, int n_in,
                              void* d_out, int out_size, void* d_ws, size_t ws_size,
                              hipStream_t stream) {
    const float* x = (const float*)d_in[0];
    const int* ei = (const int*)d_in[1];

    const int N = in_sizes[0] / 64;   // 100000
    const int E = in_sizes[1] / 2;    // 1600000
    const int* row = ei;
    const int* col = ei + E;

    const int NB = (N + BROWS - 1) >> BSHIFT;   // 782 buckets
    const int per = (E + EB - 1) / EB;          // edges per bucket-block

    // workspace layout (~21 MB)
    char* ws = (char*)d_ws;
    unsigned* sorted = (unsigned*)ws;  ws += (size_t)E * sizeof(unsigned);
    ushort4* y4      = (ushort4*)ws;   ws += (size_t)N * 128;
    int* h         = (int*)ws;   ws += (size_t)EB * NB * sizeof(int);
    int* totals    = (int*)ws;   ws += (size_t)((NB + 63) & ~63) * sizeof(int);
    float* dinv    = (float*)ws; ws += (size_t)N * sizeof(float);

    float* out = (float*)d_out;

    bucket_hist<<<EB, THREADS, 0, stream>>>(row, h, E, per, NB);
    scan_cols<<<NB, THREADS, 0, stream>>>(h, totals, NB);
    bucket_scatter<<<EB, THREADS, 0, stream>>>(row, col, h, totals, sorted, E, per, NB);
    bucket_dinv<<<NB, THREADS, 0, stream>>>(sorted, totals, (const f32x4*)x,
                                            dinv, (f32x4*)out, y4, N, NB, E);
    bucket_agg<<<NB, THREADS, 0, stream>>>(sorted, totals, (const uint4*)y4,
                                           dinv, (f32x4*)out, N, NB, E);
}

// Round 16
// 88.970 us; speedup vs baseline: 8.1907x; 8.1907x over previous
//
#include <hip/hip_runtime.h>

#define THREADS 256
#define EB 256                 // number of edge blocks for bucketing (== THREADS)
#define BSHIFT 7
#define BROWS (1 << BSHIFT)    // 128 rows per bucket
#define MAXNB 1024             // static LDS bound: supports N up to 131072
#define COLBITS 17             // col < 131072

typedef float f32x4 __attribute__((ext_vector_type(4)));

// P1: per-edge-block histogram over row buckets (LDS atomics only).
__global__ void bucket_hist(const int* __restrict__ row, int* __restrict__ h,
                            int E, int per, int NB) {
    __shared__ int lds[MAXNB];
    for (int k = threadIdx.x; k < NB; k += blockDim.x) lds[k] = 0;
    __syncthreads();
    int lo = blockIdx.x * per;
    int hi = min(E, lo + per);
    for (int i = lo + threadIdx.x; i < hi; i += blockDim.x)
        atomicAdd(&lds[row[i] >> BSHIFT], 1);
    __syncthreads();
    int* hb = h + (size_t)blockIdx.x * NB;
    for (int k = threadIdx.x; k < NB; k += blockDim.x) hb[k] = lds[k];
}

// S1: exclusive scan down each bucket column of h. One block per bucket,
// 256 threads, one element per thread. Publishes per-bucket totals.
__global__ void scan_cols(int* __restrict__ h, int* __restrict__ totals, int NB) {
    __shared__ int wsum[THREADS / 64];
    __shared__ int wexcl[THREADS / 64];
    int k = blockIdx.x;
    size_t idx = (size_t)threadIdx.x * NB + k;
    int v = h[idx];
    int lane = threadIdx.x & 63, wid = threadIdx.x >> 6;
    int s = v;
#pragma unroll
    for (int off = 1; off < 64; off <<= 1) {
        int t = __shfl_up(s, off, 64);
        if (lane >= off) s += t;
    }
    if (lane == 63) wsum[wid] = s;
    __syncthreads();
    if (threadIdx.x == 0) {
        int run = 0;
#pragma unroll
        for (int w = 0; w < THREADS / 64; ++w) { wexcl[w] = run; run += wsum[w]; }
    }
    __syncthreads();
    int excl = wexcl[wid] + s - v;
    h[idx] = excl;
    if (threadIdx.x == THREADS - 1) totals[k] = excl + v;
}

// Redundant per-block exclusive scan of totals[0..NB-1] -> bs_l[0..NB],
// bs_l[NB] = E. All blocks compute identical results from stable input.
__device__ __forceinline__ void scan_totals_lds(const int* __restrict__ totals,
                                                int* bs_l, int NB, int E) {
    __shared__ int wsum2[THREADS / 64];
    __shared__ int wexcl2[THREADS / 64];
    int base_i = threadIdx.x * 4;
    int v[4];
    int lsum = 0;
#pragma unroll
    for (int j = 0; j < 4; ++j) {
        v[j] = (base_i + j < NB) ? totals[base_i + j] : 0;
        lsum += v[j];
    }
    int lane = threadIdx.x & 63, wid = threadIdx.x >> 6;
    int ls = lsum;
#pragma unroll
    for (int off = 1; off < 64; off <<= 1) {
        int t = __shfl_up(ls, off, 64);
        if (lane >= off) ls += t;
    }
    if (lane == 63) wsum2[wid] = ls;
    __syncthreads();
    if (threadIdx.x == 0) {
        int run = 0;
#pragma unroll
        for (int w = 0; w < THREADS / 64; ++w) { wexcl2[w] = run; run += wsum2[w]; }
    }
    __syncthreads();
    int run = wexcl2[wid] + ls - lsum;
#pragma unroll
    for (int j = 0; j < 4; ++j) {
        if (base_i + j <= NB) bs_l[base_i + j] = run;
        run += v[j];
    }
    if (threadIdx.x == 0) bs_l[NB] = E;
    __syncthreads();
}

// P1b: scatter packed (lrow,col) u32 into bucket-sorted order.
__global__ void bucket_scatter(const int* __restrict__ row, const int* __restrict__ col,
                               const int* __restrict__ h, const int* __restrict__ totals,
                               unsigned* __restrict__ sorted,
                               int E, int per, int NB) {
    __shared__ int bs_l[MAXNB + 1];
    __shared__ int cur[MAXNB];
    scan_totals_lds(totals, bs_l, NB, E);
    const int* hb = h + (size_t)blockIdx.x * NB;
    for (int k = threadIdx.x; k < NB; k += blockDim.x) cur[k] = bs_l[k] + hb[k];
    __syncthreads();
    int lo = blockIdx.x * per;
    int hi = min(E, lo + per);
    for (int i = lo + threadIdx.x; i < hi; i += blockDim.x) {
        int r = row[i];
        int c = col[i];
        int pos = atomicAdd(&cur[r >> BSHIFT], 1);
        sorted[pos] = ((unsigned)(r & (BROWS - 1)) << COLBITS) | (unsigned)c;
    }
}

__device__ inline unsigned short bf16_rne(float f) {
    union { float f; unsigned u; } t; t.f = f;
    unsigned u = t.u;
    u += 0x7FFFu + ((u >> 16) & 1u);   // round to nearest even
    return (unsigned short)(u >> 16);
}

// P2 (fused): one block per bucket.
//  a) per-row counts -> row_start + dinv (global) + dls (LDS)
//  b) group cols by row into csr_col (coalesced window)
//  c) scale+emit for this bucket's 128 nodes: y = bf16(dinv*x), out[:, :64] = x
__global__ void bucket_group(const unsigned* __restrict__ sorted,
                             const int* __restrict__ totals,
                             const f32x4* __restrict__ x4,
                             int* __restrict__ csr_col, int* __restrict__ row_start,
                             float* __restrict__ dinv, f32x4* __restrict__ out4,
                             ushort4* __restrict__ y4, int N, int NB, int E) {
    __shared__ int bs_l[MAXNB + 1];
    __shared__ int hist[BROWS];
    __shared__ int cur[BROWS];
    __shared__ float dls[BROWS];
    scan_totals_lds(totals, bs_l, NB, E);
    int k = blockIdx.x;
    int base = bs_l[k];
    int cnt = bs_l[k + 1] - base;
    if (k == NB - 1 && threadIdx.x == 0) row_start[N] = E;   // sentinel
    for (int r = threadIdx.x; r < BROWS; r += blockDim.x) hist[r] = 0;
    __syncthreads();
    for (int i = threadIdx.x; i < cnt; i += blockDim.x)
        atomicAdd(&hist[sorted[base + i] >> COLBITS], 1);
    __syncthreads();
    if (threadIdx.x < 64) {
        int lane = threadIdx.x;
        int carry = 0;
#pragma unroll
        for (int b2 = 0; b2 < BROWS; b2 += 64) {
            int v = hist[b2 + lane];
            int s = v;
#pragma unroll
            for (int off = 1; off < 64; off <<= 1) {
                int t = __shfl_up(s, off, 64);
                if (lane >= off) s += t;
            }
            int pref = carry + s - v;
            cur[b2 + lane] = pref;
            float w = (v > 0) ? rsqrtf((float)v) : 0.f;
            dls[b2 + lane] = w;
            int node = (k << BSHIFT) + b2 + lane;
            if (node < N) {
                row_start[node] = base + pref;
                dinv[node] = w;
            }
            carry += __shfl(s, 63, 64);
        }
    }
    __syncthreads();
    // b) group into csr
    for (int i = threadIdx.x; i < cnt; i += blockDim.x) {
        unsigned rc = sorted[base + i];
        int r = (int)(rc >> COLBITS);
        int pos = base + atomicAdd(&cur[r], 1);
        csr_col[pos] = (int)(rc & ((1u << COLBITS) - 1));
    }
    // c) scale + copy for this bucket's 128 nodes
    int base_node = k << BSHIFT;
    for (int t = threadIdx.x; t < BROWS * 16; t += blockDim.x) {
        int nl = t >> 4, q = t & 15;
        int node = base_node + nl;
        if (node >= N) break;
        f32x4 v = x4[(size_t)node * 16 + q];
        float w = dls[nl];
        out4[(size_t)node * 32 + q] = v;
        ushort4 hh;
        hh.x = bf16_rne(v.x * w);
        hh.y = bf16_rne(v.y * w);
        hh.z = bf16_rne(v.z * w);
        hh.w = bf16_rne(v.w * w);
        y4[(size_t)node * 16 + q] = hh;
    }
}

__device__ __forceinline__ void acc_bf16x8(float a[8], uint4 v) {
    a[0] += __uint_as_float(v.x << 16);
    a[1] += __uint_as_float(v.x & 0xFFFF0000u);
    a[2] += __uint_as_float(v.y << 16);
    a[3] += __uint_as_float(v.y & 0xFFFF0000u);
    a[4] += __uint_as_float(v.z << 16);
    a[5] += __uint_as_float(v.z & 0xFFFF0000u);
    a[6] += __uint_as_float(v.w << 16);
    a[7] += __uint_as_float(v.w & 0xFFFF0000u);
}

// 8 nodes per wave: lane = (g:3 | q:3). Group g iterates its node's CSR range
// with 4 independent 16 B gathers in flight; q = 16 B chunk of the bf16 row.
__global__ void aggregate(const uint4* __restrict__ y16,
                          const int* __restrict__ row_start,
                          const int* __restrict__ csr_col,
                          const float* __restrict__ dinv,
                          f32x4* __restrict__ out4, int N) {
    int wid = threadIdx.x >> 6;
    int lane = threadIdx.x & 63;
    int g = lane >> 3;      // 0..7: node slot within wave
    int q = lane & 7;       // 0..7: 16B chunk of 128B bf16 feature row
    int node = (blockIdx.x * (blockDim.x >> 6) + wid) * 8 + g;
    if (node >= N) return;

    int s = row_start[node];
    int e = row_start[node + 1];
    float a[8] = {0.f, 0.f, 0.f, 0.f, 0.f, 0.f, 0.f, 0.f};
    int i = s;
    for (; i + 3 < e; i += 4) {
        int c0 = csr_col[i];
        int c1 = csr_col[i + 1];
        int c2 = csr_col[i + 2];
        int c3 = csr_col[i + 3];
        uint4 v0 = y16[(size_t)c0 * 8 + q];
        uint4 v1 = y16[(size_t)c1 * 8 + q];
        uint4 v2 = y16[(size_t)c2 * 8 + q];
        uint4 v3 = y16[(size_t)c3 * 8 + q];
        acc_bf16x8(a, v0);
        acc_bf16x8(a, v1);
        acc_bf16x8(a, v2);
        acc_bf16x8(a, v3);
    }
    for (; i < e; ++i) {
        int c = csr_col[i];
        acc_bf16x8(a, y16[(size_t)c * 8 + q]);
    }
    float w0 = dinv[node];
    f32x4 r0 = {a[0] * w0, a[1] * w0, a[2] * w0, a[3] * w0};
    f32x4 r1 = {a[4] * w0, a[5] * w0, a[6] * w0, a[7] * w0};
    size_t obase = (size_t)node * 32 + 16 + q * 2;
    out4[obase] = r0;
    out4[obase + 1] = r1;
}

extern "C" void kernel_launch(void* const* d_in, const int* in_sizes, int n_in,
                              void* d_out, int out_size, void* d_ws, size_t ws_size,
                              hipStream_t stream) {
    const float* x = (const float*)d_in[0];
    const int* ei = (const int*)d_in[1];

    const int N = in_sizes[0] / 64;   // 100000
    const int E = in_sizes[1] / 2;    // 1600000
    const int* row = ei;
    const int* col = ei + E;

    const int NB = (N + BROWS - 1) >> BSHIFT;   // 782 buckets
    const int per = (E + EB - 1) / EB;          // edges per bucket-block

    // workspace layout (~27 MB): y4 is its own slab (bucket_group writes it
    // while it and other blocks still read sorted).
    char* ws = (char*)d_ws;
    unsigned* sorted = (unsigned*)ws;  ws += (size_t)E * sizeof(unsigned);
    ushort4* y4      = (ushort4*)ws;   ws += (size_t)N * 128;
    int* h         = (int*)ws;   ws += (size_t)EB * NB * sizeof(int);
    int* totals    = (int*)ws;   ws += (size_t)((NB + 63) & ~63) * sizeof(int);
    int* row_start = (int*)ws;   ws += (size_t)(N + 1) * sizeof(int);
    float* dinv    = (float*)ws; ws += (size_t)N * sizeof(float);
    int* csr_col   = (int*)ws;   // E ints

    float* out = (float*)d_out;

    bucket_hist<<<EB, THREADS, 0, stream>>>(row, h, E, per, NB);
    scan_cols<<<NB, THREADS, 0, stream>>>(h, totals, NB);
    bucket_scatter<<<EB, THREADS, 0, stream>>>(row, col, h, totals, sorted, E, per, NB);
    bucket_group<<<NB, THREADS, 0, stream>>>(sorted, totals, (const f32x4*)x,
                                             csr_col, row_start, dinv,
                                             (f32x4*)out, y4, N, NB, E);

    int nodes_per_block = (THREADS / 64) * 8;   // 32
    int blocks = (N + nodes_per_block - 1) / nodes_per_block;
    aggregate<<<blocks, THREADS, 0, stream>>>((const uint4*)y4, row_start, csr_col,
                                              dinv, (f32x4*)out, N);
}